// Round 16
// baseline (171.572 us; speedup 1.0000x reference)
//
#include <hip/hip_runtime.h>
#include <hip/hip_bf16.h>

typedef __attribute__((ext_vector_type(8))) short  svec8;
typedef __attribute__((ext_vector_type(4))) short  svec4;
typedef __attribute__((ext_vector_type(8))) __bf16 bfvec8;
typedef __attribute__((ext_vector_type(4))) float  f32x4;
typedef __attribute__((ext_vector_type(2))) float  f32x2;
typedef __attribute__((ext_vector_type(4))) unsigned uvec4;
typedef __attribute__((ext_vector_type(2))) unsigned uivec2;

#define LN_EPS 1e-3f

__device__ __forceinline__ short f2bf(float f) {
  union { float f; unsigned u; } v; v.f = f;
  unsigned u = v.u;
  u += 0x7fff + ((u >> 16) & 1);   // round-to-nearest-even
  return (short)(u >> 16);
}

__device__ __forceinline__ unsigned pk2(float a, float b) {
  unsigned short ua = __builtin_bit_cast(unsigned short, (__bf16)a);
  unsigned short ub = __builtin_bit_cast(unsigned short, (__bf16)b);
  return (unsigned)ua | ((unsigned)ub << 16);
}

__device__ __forceinline__ f32x2 up2(unsigned w) {   // u32 of 2 bf16 -> f32x2
  f32x2 r;
  r[0] = __builtin_bit_cast(float, w << 16);
  r[1] = __builtin_bit_cast(float, w & 0xffff0000u);
  return r;
}

__device__ __forceinline__ f32x4 mfma16(svec8 a, svec8 b, f32x4 c) {
  return __builtin_amdgcn_mfma_f32_16x16x32_bf16(
      __builtin_bit_cast(bfvec8, a), __builtin_bit_cast(bfvec8, b), c, 0, 0, 0);
}

// ================= setup: pack 6 weights + CSR offsets + folded constants, ONE launch ====
__global__ __launch_bounds__(256) void setup_kernel(
    const float* __restrict__ pW1, const float* __restrict__ pW2,
    const float* __restrict__ pg1,
    const float* __restrict__ mW1, const float* __restrict__ mW2,
    const float* __restrict__ mW3,
    short* __restrict__ w1qp, short* __restrict__ w1mp,
    short* __restrict__ w2p,  short* __restrict__ mw1p,
    short* __restrict__ mw2p, short* __restrict__ mw3p,
    const int* __restrict__ row, int E, int N, int* __restrict__ off,
    const float* __restrict__ g1, const float* __restrict__ be1,
    const float* __restrict__ b2, const float* __restrict__ g2,
    const float* __restrict__ w3, const float* __restrict__ be2,
    const float* __restrict__ b3,
    float* __restrict__ s2, float* __restrict__ b2pv,
    float* __restrict__ gw, float* __restrict__ consts, int nboff)
{
  const int b = blockIdx.x;
  const int tid = threadIdx.x;
  if (b < 384) {                       // ---- pack weights: 6 * 16384 elems ----
    int idx = b * 256 + tid;
    int which = idx >> 14, p = idx & 16383;
    int j = p & 7, lane = (p >> 3) & 63, t = p >> 9;
    int nf = t & 7, ks = t >> 3;
    int k = ks * 32 + (lane >> 4) * 8 + j;
    int n = nf * 16 + (lane & 15);
    const float* src; short* dst; float scale = 1.f;
    switch (which) {
      case 0:  src = pW1;         dst = w1qp; break;
      case 1:  src = pW1 + 16384; dst = w1mp; break;
      case 2:  src = pW2;         dst = w2p; scale = pg1[k]; break;
      case 3:  src = mW1;         dst = mw1p; break;
      case 4:  src = mW2;         dst = mw2p; break;
      default: src = mW3;         dst = mw3p; break;
    }
    dst[p] = f2bf(scale * src[k * 128 + n]);
  } else if (b < 384 + nboff) {        // ---- CSR offsets via binary search ----
    int i = (b - 384) * 256 + tid;
    if (i > N) return;
    int lo = 0, hi = E;
    while (lo < hi) { int mid = (lo + hi) >> 1; if (row[mid] < i) lo = mid + 1; else hi = mid; }
    off[i] = lo;
  } else {                             // ---- folded constants ----
    __shared__ float tmp[256];
    int n = tid;
    if (n < 128) {
      float s = 0.f, bb = 0.f;
      for (int k = 0; k < 128; ++k) {
        float w = pW2[k * 128 + n];
        s  = fmaf(g1[k],  w, s);
        bb = fmaf(be1[k], w, bb);
      }
      s2[n]   = s;
      b2pv[n] = bb + b2[n];
      float g = g2[n] * w3[n];
      gw[n] = g;
      tmp[n]       = g;
      tmp[128 + n] = be2[n] * w3[n];
    }
    __syncthreads();
    if (n == 0) {
      float a = 0.f, c = 0.f;
      for (int i = 0; i < 128; ++i) { a += tmp[i]; c += tmp[128 + i]; }
      consts[0] = a;
      consts[1] = c + b3[0];
    }
  }
}

// ======== node kernel v2: wave-autonomous — each wave owns 16 rows x all 128 cols ========
__global__ __launch_bounds__(256) void node_kernel(
    const float* __restrict__ mem, const float* __restrict__ query,
    const short* __restrict__ w1p, const short* __restrict__ w2p, const short* __restrict__ w3p,
    const short* __restrict__ wmp, const short* __restrict__ wqp,
    const float* __restrict__ b1v, const float* __restrict__ b2v, const float* __restrict__ b3v,
    const float* __restrict__ g1v, const float* __restrict__ be1v,
    const float* __restrict__ g2v, const float* __restrict__ be2v,
    const float* __restrict__ pb1,
    short* __restrict__ mhb, short* __restrict__ mwt, short* __restrict__ qwt,
    int N, int nbm)
{
  __shared__ char Hs[4][4096];   // wave-private 16x128 bf16 slices (swizzled)

  const int tid  = threadIdx.x;
  const int wv   = tid >> 6;
  const int lane = tid & 63;
  const int g    = lane >> 4;
  const int l16  = lane & 15;
  const bool is_mem = (blockIdx.x < nbm);
  const int r0   = (is_mem ? blockIdx.x : blockIdx.x - nbm) * 64 + wv * 16;
  const float* src = is_mem ? mem : query;

  int grow = r0 + l16; if (grow >= N) grow = N - 1;
  const float* xrow = src + (size_t)grow * 128 + g * 8;
  svec8 xf[4];
  #pragma unroll
  for (int ks = 0; ks < 4; ++ks) {
    f32x4 a = *(const f32x4*)(xrow + ks * 32);
    f32x4 b = *(const f32x4*)(xrow + ks * 32 + 4);
    uvec4 u;
    u[0] = pk2(a[0], a[1]); u[1] = pk2(a[2], a[3]);
    u[2] = pk2(b[0], b[1]); u[3] = pk2(b[2], b[3]);
    xf[ks] = __builtin_bit_cast(svec8, u);
  }

  if (!is_mem) {
    f32x4 acc[8];
    #pragma unroll
    for (int nf = 0; nf < 8; ++nf) { f32x4 z = {0.f,0.f,0.f,0.f}; acc[nf] = z; }
    #pragma unroll
    for (int ks = 0; ks < 4; ++ks)
      #pragma unroll
      for (int nf = 0; nf < 8; ++nf) {
        svec8 bw = *(const svec8*)(wqp + (((ks * 8 + nf) * 64 + lane) << 3));
        acc[nf] = mfma16(xf[ks], bw, acc[nf]);
      }
    #pragma unroll
    for (int nf = 0; nf < 8; ++nf) {
      float bi = pb1[nf * 16 + l16];
      #pragma unroll
      for (int r = 0; r < 4; ++r) {
        int gr = r0 + g * 4 + r;
        if (gr < N) qwt[(size_t)gr * 128 + nf * 16 + l16] = f2bf(acc[nf][r] + bi);
      }
    }
    return;
  }

  f32x4 acc[8], accm[8];
  #pragma unroll
  for (int nf = 0; nf < 8; ++nf) { f32x4 z = {0.f,0.f,0.f,0.f}; acc[nf] = z; accm[nf] = z; }
  #pragma unroll
  for (int ks = 0; ks < 4; ++ks)
    #pragma unroll
    for (int nf = 0; nf < 8; ++nf) {
      svec8 bw = *(const svec8*)(w1p + (((ks * 8 + nf) * 64 + lane) << 3));
      svec8 bm = *(const svec8*)(wmp + (((ks * 8 + nf) * 64 + lane) << 3));
      acc[nf]  = mfma16(xf[ks], bw, acc[nf]);
      accm[nf] = mfma16(xf[ks], bm, accm[nf]);
    }
  #pragma unroll
  for (int nf = 0; nf < 8; ++nf)
    #pragma unroll
    for (int r = 0; r < 4; ++r) {
      int gr = r0 + g * 4 + r;
      if (gr < N) mwt[(size_t)gr * 128 + nf * 16 + l16] = f2bf(accm[nf][r]);
    }

  char* slice = Hs[wv];

  float ps[4] = {0,0,0,0}, pq[4] = {0,0,0,0};
  #pragma unroll
  for (int nf = 0; nf < 8; ++nf) {
    float bi = b1v[nf * 16 + l16];
    #pragma unroll
    for (int r = 0; r < 4; ++r) {
      float y = fmaxf(acc[nf][r] + bi, 0.f);
      acc[nf][r] = y;
      ps[r] += y;
      pq[r] = fmaf(y, y, pq[r]);
    }
  }
  #pragma unroll
  for (int mk = 1; mk <= 8; mk <<= 1)
    #pragma unroll
    for (int r = 0; r < 4; ++r) {
      ps[r] += __shfl_xor(ps[r], mk, 64);
      pq[r] += __shfl_xor(pq[r], mk, 64);
    }
  #pragma unroll
  for (int r = 0; r < 4; ++r) {
    float mu = ps[r] * (1.f / 128.f);
    float var = fmaxf(pq[r] * (1.f / 128.f) - mu * mu, 0.f);
    float rstd = rsqrtf(var + LN_EPS);
    int rloc = g * 4 + r;
    #pragma unroll
    for (int nf = 0; nf < 8; ++nf) {
      float ga = g1v[nf * 16 + l16], bb = be1v[nf * 16 + l16];
      float z = (acc[nf][r] - mu) * rstd * ga + bb;
      int byt = (rloc * 256 + (nf * 16 + l16) * 2) ^ ((rloc & 7) << 4);
      *(short*)(slice + byt) = f2bf(z);
    }
  }

  svec8 hf[4];
  #pragma unroll
  for (int ks = 0; ks < 4; ++ks) {
    int byt = (l16 * 256 + (ks * 32 + g * 8) * 2) ^ ((l16 & 7) << 4);
    hf[ks] = *(const svec8*)(slice + byt);
  }
  f32x4 acc2[8];
  #pragma unroll
  for (int nf = 0; nf < 8; ++nf) { f32x4 z = {0.f,0.f,0.f,0.f}; acc2[nf] = z; }
  #pragma unroll
  for (int ks = 0; ks < 4; ++ks)
    #pragma unroll
    for (int nf = 0; nf < 8; ++nf) {
      svec8 bw = *(const svec8*)(w2p + (((ks * 8 + nf) * 64 + lane) << 3));
      acc2[nf] = mfma16(hf[ks], bw, acc2[nf]);
    }

  #pragma unroll
  for (int r = 0; r < 4; ++r) { ps[r] = 0.f; pq[r] = 0.f; }
  #pragma unroll
  for (int nf = 0; nf < 8; ++nf) {
    float bi = b2v[nf * 16 + l16];
    #pragma unroll
    for (int r = 0; r < 4; ++r) {
      float y = fmaxf(acc2[nf][r] + bi, 0.f);
      acc2[nf][r] = y;
      ps[r] += y;
      pq[r] = fmaf(y, y, pq[r]);
    }
  }
  #pragma unroll
  for (int mk = 1; mk <= 8; mk <<= 1)
    #pragma unroll
    for (int r = 0; r < 4; ++r) {
      ps[r] += __shfl_xor(ps[r], mk, 64);
      pq[r] += __shfl_xor(pq[r], mk, 64);
    }
  #pragma unroll
  for (int r = 0; r < 4; ++r) {
    float mu = ps[r] * (1.f / 128.f);
    float var = fmaxf(pq[r] * (1.f / 128.f) - mu * mu, 0.f);
    float rstd = rsqrtf(var + LN_EPS);
    int rloc = g * 4 + r;
    #pragma unroll
    for (int nf = 0; nf < 8; ++nf) {
      float ga = g2v[nf * 16 + l16], bb = be2v[nf * 16 + l16];
      float z = (acc2[nf][r] - mu) * rstd * ga + bb;
      int byt = (rloc * 256 + (nf * 16 + l16) * 2) ^ ((rloc & 7) << 4);
      *(short*)(slice + byt) = f2bf(z);
    }
  }

  #pragma unroll
  for (int ks = 0; ks < 4; ++ks) {
    int byt = (l16 * 256 + (ks * 32 + g * 8) * 2) ^ ((l16 & 7) << 4);
    hf[ks] = *(const svec8*)(slice + byt);
  }
  f32x4 acc3[8];
  #pragma unroll
  for (int nf = 0; nf < 8; ++nf) { f32x4 z = {0.f,0.f,0.f,0.f}; acc3[nf] = z; }
  #pragma unroll
  for (int ks = 0; ks < 4; ++ks)
    #pragma unroll
    for (int nf = 0; nf < 8; ++nf) {
      svec8 bw = *(const svec8*)(w3p + (((ks * 8 + nf) * 64 + lane) << 3));
      acc3[nf] = mfma16(hf[ks], bw, acc3[nf]);
    }
  #pragma unroll
  for (int nf = 0; nf < 8; ++nf) {
    float bi = b3v[nf * 16 + l16];
    #pragma unroll
    for (int r = 0; r < 4; ++r) {
      int gr = r0 + g * 4 + r;
      if (gr < N) mhb[(size_t)gr * 128 + nf * 16 + l16] = f2bf(acc3[nf][r] + bi);
    }
  }
}

// ---- relu(q+m) with packed f32; emits B-frags + sum/sumsq ----
__device__ __forceinline__ void relu_stats(const svec8* qv, const svec8* mv,
                                           svec8* yf, float& ps_o, float& pq_o) {
  f32x2 psv = {0.f, 0.f}, pqv = {0.f, 0.f};
  #pragma unroll
  for (int ks2 = 0; ks2 < 4; ++ks2) {
    uvec4 qu = __builtin_bit_cast(uvec4, qv[ks2]);
    uvec4 mu = __builtin_bit_cast(uvec4, mv[ks2]);
    uvec4 u;
    #pragma unroll
    for (int p = 0; p < 4; ++p) {
      f32x2 y = __builtin_elementwise_max(up2(qu[p]) + up2(mu[p]), (f32x2){0.f, 0.f});
      psv += y;
      pqv += y * y;
      u[p] = pk2(y[0], y[1]);
    }
    yf[ks2] = __builtin_bit_cast(svec8, u);
  }
  float ps = psv[0] + psv[1], pq = pqv[0] + pqv[1];
  ps += __shfl_xor(ps, 16, 64); pq += __shfl_xor(pq, 16, 64);
  ps += __shfl_xor(ps, 32, 64); pq += __shfl_xor(pq, 32, 64);
  ps_o = ps; pq_o = pq;
}

// ---------------- edge MLP: EG=2, W2' in LDS, nf-split ----------
__global__ __launch_bounds__(256, 4) void edge_mlp_kernel(
    const short* __restrict__ qwt, const short* __restrict__ mwt,
    const int* __restrict__ rowi, const int* __restrict__ coli,
    const short* __restrict__ w2p,
    const float* __restrict__ s2v, const float* __restrict__ b2pv,
    const float* __restrict__ gwv, const float* __restrict__ consts,
    float* __restrict__ hout, int E)
{
  __shared__ short w2s[16384];   // 32 KB: all W2' fragments

  const int tid  = threadIdx.x;
  const int wv   = tid >> 6;
  const int lane = tid & 63;
  const int g    = lane >> 4;
  const int l16  = lane & 15;

  // bijective XCD-aware block swizzle (m204)
  const int nb  = gridDim.x;
  const int q8  = nb >> 3, r8 = nb & 7;
  const int xcd = blockIdx.x & 7, sub = blockIdx.x >> 3;
  const int bid = (xcd < r8 ? xcd * (q8 + 1) : r8 * (q8 + 1) + (xcd - r8) * q8) + sub;

  // stage W2' fragments (linear copy)
  #pragma unroll
  for (int it = 0; it < 8; ++it) {
    int o = (it * 256 + tid) * 8;    // shorts
    *(f32x4*)(w2s + o) = *(const f32x4*)(w2p + o);
  }
  __syncthreads();

  const int eb = bid * 128 + wv * 32;
  const int e0 = eb + l16, e1 = eb + 16 + l16;
  const bool v0 = (e0 < E), v1 = (e1 < E);
  const int ee0 = v0 ? e0 : 0, ee1 = v1 ? e1 : 0;
  const short* q0 = qwt + (size_t)rowi[ee0] * 128 + g * 8;
  const short* m0 = mwt + (size_t)coli[ee0] * 128 + g * 8;
  const short* q1 = qwt + (size_t)rowi[ee1] * 128 + g * 8;
  const short* m1 = mwt + (size_t)coli[ee1] * 128 + g * 8;

  // issue all 16 gathers up front
  svec8 qv0[4], mv0[4], qv1[4], mv1[4];
  #pragma unroll
  for (int ks2 = 0; ks2 < 4; ++ks2) {
    qv0[ks2] = *(const svec8*)(q0 + ks2 * 32);
    mv0[ks2] = *(const svec8*)(m0 + ks2 * 32);
    qv1[ks2] = *(const svec8*)(q1 + ks2 * 32);
    mv1[ks2] = *(const svec8*)(m1 + ks2 * 32);
  }

  svec8 yf0[4], yf1[4];
  float ps0, pq0, ps1, pq1;
  relu_stats(qv0, mv0, yf0, ps0, pq0);
  relu_stats(qv1, mv1, yf1, ps1, pq1);
  float mu1_0   = ps0 * (1.f / 128.f);
  float rstd1_0 = rsqrtf(fmaxf(pq0 * (1.f / 128.f) - mu1_0 * mu1_0, 0.f) + LN_EPS);
  float mu1_1   = ps1 * (1.f / 128.f);
  float rstd1_1 = rsqrtf(fmaxf(pq1 * (1.f / 128.f) - mu1_1 * mu1_1, 0.f) + LN_EPS);
  float nmu0 = -rstd1_0 * mu1_0;
  float nmu1 = -rstd1_1 * mu1_1;

  // running epilogue stats carried across the two nf-halves
  f32x2 Aps = {0.f,0.f}, Apq = {0.f,0.f}, Apw = {0.f,0.f};
  f32x2 Bps = {0.f,0.f}, Bpq = {0.f,0.f}, Bpw = {0.f,0.f};

  #pragma unroll
  for (int half = 0; half < 2; ++half) {
    const int nfb = half * 4;
    f32x4 acc2a[4], acc2b[4];
    #pragma unroll
    for (int nf = 0; nf < 4; ++nf) { f32x4 z = {0.f,0.f,0.f,0.f}; acc2a[nf] = z; acc2b[nf] = z; }
    __builtin_amdgcn_s_setprio(1);
    #pragma unroll
    for (int ks2 = 0; ks2 < 4; ++ks2) {
      #pragma unroll
      for (int nf = 0; nf < 4; ++nf) {
        svec8 w = *(const svec8*)(w2s + (((ks2 * 8 + nfb + nf) * 64 + lane) << 3));
        acc2a[nf] = mfma16(w, yf0[ks2], acc2a[nf]);
        acc2b[nf] = mfma16(w, yf1[ks2], acc2b[nf]);
      }
    }
    __builtin_amdgcn_s_setprio(0);
    // partial folded epilogue for this nf-half
    #pragma unroll
    for (int nf = 0; nf < 4; ++nf) {
      f32x4 s2 = *(const f32x4*)(s2v  + (nfb + nf) * 16 + g * 4);
      f32x4 bb = *(const f32x4*)(b2pv + (nfb + nf) * 16 + g * 4);
      f32x4 gw = *(const f32x4*)(gwv  + (nfb + nf) * 16 + g * 4);
      #pragma unroll
      for (int p = 0; p < 2; ++p) {
        f32x2 s2p = { s2[2*p], s2[2*p+1] };
        f32x2 bbp = { bb[2*p], bb[2*p+1] };
        f32x2 gwp = { gw[2*p], gw[2*p+1] };
        f32x2 aa  = { acc2a[nf][2*p], acc2a[nf][2*p+1] };
        f32x2 ab  = { acc2b[nf][2*p], acc2b[nf][2*p+1] };
        f32x2 ha = (f32x2){rstd1_0, rstd1_0} * aa + ((f32x2){nmu0, nmu0} * s2p + bbp);
        f32x2 hb = (f32x2){rstd1_1, rstd1_1} * ab + ((f32x2){nmu1, nmu1} * s2p + bbp);
        f32x2 ya = __builtin_elementwise_max(ha, (f32x2){0.f, 0.f});
        f32x2 yb = __builtin_elementwise_max(hb, (f32x2){0.f, 0.f});
        Aps += ya; Apq += ya * ya; Apw += ya * gwp;
        Bps += yb; Bpq += yb * yb; Bpw += yb * gwp;
      }
    }
  }

  float Sgw = consts[0], cb = consts[1];
  float ps2a = Aps[0] + Aps[1], pq2a = Apq[0] + Apq[1], pw2a = Apw[0] + Apw[1];
  float ps2b = Bps[0] + Bps[1], pq2b = Bpq[0] + Bpq[1], pw2b = Bpw[0] + Bpw[1];
  ps2a += __shfl_xor(ps2a, 16, 64); pq2a += __shfl_xor(pq2a, 16, 64); pw2a += __shfl_xor(pw2a, 16, 64);
  ps2a += __shfl_xor(ps2a, 32, 64); pq2a += __shfl_xor(pq2a, 32, 64); pw2a += __shfl_xor(pw2a, 32, 64);
  ps2b += __shfl_xor(ps2b, 16, 64); pq2b += __shfl_xor(pq2b, 16, 64); pw2b += __shfl_xor(pw2b, 16, 64);
  ps2b += __shfl_xor(ps2b, 32, 64); pq2b += __shfl_xor(pq2b, 32, 64); pw2b += __shfl_xor(pw2b, 32, 64);
  {
    float mu2 = ps2a * (1.f / 128.f);
    float var2 = fmaxf(pq2a * (1.f / 128.f) - mu2 * mu2, 0.f);
    float rstd2 = rsqrtf(var2 + LN_EPS);
    float p3 = fmaf(rstd2, pw2a - mu2 * Sgw, cb);
    if (lane < 16 && v0) hout[e0] = tanhf(p3);
  }
  {
    float mu2 = ps2b * (1.f / 128.f);
    float var2 = fmaxf(pq2b * (1.f / 128.f) - mu2 * mu2, 0.f);
    float rstd2 = rsqrtf(var2 + LN_EPS);
    float p3 = fmaf(rstd2, pw2b - mu2 * Sgw, cb);
    if (lane < 16 && v1) hout[e1] = tanhf(p3);
  }
}

// -------- segment sum: half-wave per edge (2 edges concurrent), 4 cols/lane, bf16 -------
__global__ __launch_bounds__(256) void segsum_kernel(
    const int* __restrict__ off, const int* __restrict__ coli,
    const float* __restrict__ hbuf, const short* __restrict__ mhb,
    float* __restrict__ out, int N)
{
  int wv = threadIdx.x >> 6, lane = threadIdx.x & 63;
  int i = blockIdx.x * 4 + wv;
  if (i >= N) return;
  int s = __builtin_amdgcn_readfirstlane(off[i]);
  int e = __builtin_amdgcn_readfirstlane(off[i + 1]);
  int half = lane >> 5, l32 = lane & 31;
  f32x4 acc = {0.f, 0.f, 0.f, 0.f};
  int k = s + half;
  for (; k + 14 < e; k += 16) {
    float h[8]; uivec2 w[8];
    #pragma unroll
    for (int u = 0; u < 8; ++u) {
      int idx = k + 2 * u;
      h[u] = hbuf[idx];
      w[u] = *(const uivec2*)(mhb + (size_t)coli[idx] * 128 + l32 * 4);
    }
    #pragma unroll
    for (int u = 0; u < 8; ++u) {
      f32x2 lo = up2(w[u][0]), hi = up2(w[u][1]);
      acc[0] = fmaf(h[u], lo[0], acc[0]);
      acc[1] = fmaf(h[u], lo[1], acc[1]);
      acc[2] = fmaf(h[u], hi[0], acc[2]);
      acc[3] = fmaf(h[u], hi[1], acc[3]);
    }
  }
  for (; k < e; k += 2) {
    float h = hbuf[k];
    uivec2 w = *(const uivec2*)(mhb + (size_t)coli[k] * 128 + l32 * 4);
    f32x2 lo = up2(w[0]), hi = up2(w[1]);
    acc[0] = fmaf(h, lo[0], acc[0]);
    acc[1] = fmaf(h, lo[1], acc[1]);
    acc[2] = fmaf(h, hi[0], acc[2]);
    acc[3] = fmaf(h, hi[1], acc[3]);
  }
  #pragma unroll
  for (int q = 0; q < 4; ++q) acc[q] += __shfl_xor(acc[q], 32, 64);
  if (half == 0) *(f32x4*)(out + (size_t)i * 128 + l32 * 4) = acc;
}

extern "C" void kernel_launch(void* const* d_in, const int* in_sizes, int n_in,
                              void* d_out, int out_size, void* d_ws, size_t ws_size,
                              hipStream_t stream) {
  const float* query = (const float*)d_in[0];
  const float* mem   = (const float*)d_in[1];
  const int*   row   = (const int*)d_in[2];
  const int*   col   = (const int*)d_in[3];
  const float* pW1 = (const float*)d_in[4];  const float* pb1 = (const float*)d_in[5];
  const float* pW2 = (const float*)d_in[6];  const float* pb2 = (const float*)d_in[7];
  const float* pW3 = (const float*)d_in[8];  const float* pb3 = (const float*)d_in[9];
  const float* pg1 = (const float*)d_in[10]; const float* pbe1 = (const float*)d_in[11];
  const float* pg2 = (const float*)d_in[12]; const float* pbe2 = (const float*)d_in[13];
  const float* mW1 = (const float*)d_in[14]; const float* mb1 = (const float*)d_in[15];
  const float* mW2 = (const float*)d_in[16]; const float* mb2 = (const float*)d_in[17];
  const float* mW3 = (const float*)d_in[18]; const float* mb3 = (const float*)d_in[19];
  const float* mg1 = (const float*)d_in[20]; const float* mbe1 = (const float*)d_in[21];
  const float* mg2 = (const float*)d_in[22]; const float* mbe2 = (const float*)d_in[23];

  const int N = in_sizes[0] / 128;
  const int E = in_sizes[2];

  char* ws = (char*)d_ws;
  short* w1qp = (short*)(ws + 0);        // 32768 B
  short* w1mp = (short*)(ws + 32768);    // 32768 B
  short* w2p  = (short*)(ws + 65536);    // 32768 B (scaled by g1)
  short* mw1p = (short*)(ws + 98304);    // 32768 B
  short* mw2p = (short*)(ws + 131072);   // 32768 B
  short* mw3p = (short*)(ws + 163840);   // 32768 B
  float* s2v  = (float*)(ws + 196608);   // 512 B
  float* b2pv = (float*)(ws + 197120);   // 512 B
  float* gwv  = (float*)(ws + 197632);   // 512 B
  float* cons = (float*)(ws + 198144);   // 64 B
  int*   offs = (int*)(ws + 198208);     // (N+1)*4
  size_t o = 198208 + (((size_t)(N + 1) * 4 + 255) / 256) * 256;
  short* qwt  = (short*)(ws + o);  o += (size_t)N * 128 * 2;   // bf16 q@W1t + b1
  short* mwt  = (short*)(ws + o);  o += (size_t)N * 128 * 2;   // bf16 m@W1b
  short* mhb  = (short*)(ws + o);  o += (size_t)N * 128 * 2;   // bf16 mem_head
  float* hbuf = (float*)(ws + o);  o += (size_t)E * 4;

  if (ws_size < o) return;

  const int nboff = (N + 1 + 255) / 256;
  setup_kernel<<<384 + nboff + 1, 256, 0, stream>>>(
      pW1, pW2, pg1, mW1, mW2, mW3, w1qp, w1mp, w2p, mw1p, mw2p, mw3p,
      row, E, N, offs,
      pg1, pbe1, pb2, pg2, pW3, pbe2, pb3, s2v, b2pv, gwv, cons, nboff);

  const int nbm = (N + 63) / 64;
  node_kernel<<<2 * nbm, 256, 0, stream>>>(
      mem, query, mw1p, mw2p, mw3p, w1mp, w1qp,
      mb1, mb2, mb3, mg1, mbe1, mg2, mbe2, pb1,
      mhb, mwt, qwt, N, nbm);

  edge_mlp_kernel<<<(E + 127) / 128, 256, 0, stream>>>(
      qwt, mwt, row, col, w2p, s2v, b2pv, gwv, cons, hbuf, E);

  segsum_kernel<<<(N + 3) / 4, 256, 0, stream>>>(offs, col, hbuf, mhb, (float*)d_out, N);
}

// Round 17
// 164.841 us; speedup vs baseline: 1.0408x; 1.0408x over previous
//
#include <hip/hip_runtime.h>
#include <hip/hip_bf16.h>

typedef __attribute__((ext_vector_type(8))) short  svec8;
typedef __attribute__((ext_vector_type(4))) short  svec4;
typedef __attribute__((ext_vector_type(8))) __bf16 bfvec8;
typedef __attribute__((ext_vector_type(4))) float  f32x4;
typedef __attribute__((ext_vector_type(2))) float  f32x2;
typedef __attribute__((ext_vector_type(4))) unsigned uvec4;

#define LN_EPS 1e-3f

__device__ __forceinline__ short f2bf(float f) {
  union { float f; unsigned u; } v; v.f = f;
  unsigned u = v.u;
  u += 0x7fff + ((u >> 16) & 1);   // round-to-nearest-even
  return (short)(u >> 16);
}

__device__ __forceinline__ unsigned pk2(float a, float b) {
  unsigned short ua = __builtin_bit_cast(unsigned short, (__bf16)a);
  unsigned short ub = __builtin_bit_cast(unsigned short, (__bf16)b);
  return (unsigned)ua | ((unsigned)ub << 16);
}

__device__ __forceinline__ f32x2 up2(unsigned w) {   // u32 of 2 bf16 -> f32x2
  f32x2 r;
  r[0] = __builtin_bit_cast(float, w << 16);
  r[1] = __builtin_bit_cast(float, w & 0xffff0000u);
  return r;
}

__device__ __forceinline__ f32x4 mfma16(svec8 a, svec8 b, f32x4 c) {
  return __builtin_amdgcn_mfma_f32_16x16x32_bf16(
      __builtin_bit_cast(bfvec8, a), __builtin_bit_cast(bfvec8, b), c, 0, 0, 0);
}

// ================= setup: pack 6 weights + CSR offsets + folded constants, ONE launch ====
__global__ __launch_bounds__(256) void setup_kernel(
    const float* __restrict__ pW1, const float* __restrict__ pW2,
    const float* __restrict__ pg1,
    const float* __restrict__ mW1, const float* __restrict__ mW2,
    const float* __restrict__ mW3,
    short* __restrict__ w1qp, short* __restrict__ w1mp,
    short* __restrict__ w2p,  short* __restrict__ mw1p,
    short* __restrict__ mw2p, short* __restrict__ mw3p,
    const int* __restrict__ row, int E, int N, int* __restrict__ off,
    const float* __restrict__ g1, const float* __restrict__ be1,
    const float* __restrict__ b2, const float* __restrict__ g2,
    const float* __restrict__ w3, const float* __restrict__ be2,
    const float* __restrict__ b3,
    float* __restrict__ s2, float* __restrict__ b2pv,
    float* __restrict__ gw, float* __restrict__ consts, int nboff)
{
  const int b = blockIdx.x;
  const int tid = threadIdx.x;
  if (b < 384) {                       // ---- pack weights: 6 * 16384 elems ----
    int idx = b * 256 + tid;
    int which = idx >> 14, p = idx & 16383;
    int j = p & 7, lane = (p >> 3) & 63, t = p >> 9;
    int nf = t & 7, ks = t >> 3;
    int k = ks * 32 + (lane >> 4) * 8 + j;
    int n = nf * 16 + (lane & 15);
    const float* src; short* dst; float scale = 1.f;
    switch (which) {
      case 0:  src = pW1;         dst = w1qp; break;
      case 1:  src = pW1 + 16384; dst = w1mp; break;
      case 2:  src = pW2;         dst = w2p; scale = pg1[k]; break;
      case 3:  src = mW1;         dst = mw1p; break;
      case 4:  src = mW2;         dst = mw2p; break;
      default: src = mW3;         dst = mw3p; break;
    }
    dst[p] = f2bf(scale * src[k * 128 + n]);
  } else if (b < 384 + nboff) {        // ---- CSR offsets via binary search ----
    int i = (b - 384) * 256 + tid;
    if (i > N) return;
    int lo = 0, hi = E;
    while (lo < hi) { int mid = (lo + hi) >> 1; if (row[mid] < i) lo = mid + 1; else hi = mid; }
    off[i] = lo;
  } else {                             // ---- folded constants ----
    __shared__ float tmp[256];
    int n = tid;
    if (n < 128) {
      float s = 0.f, bb = 0.f;
      for (int k = 0; k < 128; ++k) {
        float w = pW2[k * 128 + n];
        s  = fmaf(g1[k],  w, s);
        bb = fmaf(be1[k], w, bb);
      }
      s2[n]   = s;
      b2pv[n] = bb + b2[n];
      float g = g2[n] * w3[n];
      gw[n] = g;
      tmp[n]       = g;
      tmp[128 + n] = be2[n] * w3[n];
    }
    __syncthreads();
    if (n == 0) {
      float a = 0.f, c = 0.f;
      for (int i = 0; i < 128; ++i) { a += tmp[i]; c += tmp[128 + i]; }
      consts[0] = a;
      consts[1] = c + b3[0];
    }
  }
}

// ======== node kernel v2: wave-autonomous — each wave owns 16 rows x all 128 cols ========
__global__ __launch_bounds__(256) void node_kernel(
    const float* __restrict__ mem, const float* __restrict__ query,
    const short* __restrict__ w1p, const short* __restrict__ w2p, const short* __restrict__ w3p,
    const short* __restrict__ wmp, const short* __restrict__ wqp,
    const float* __restrict__ b1v, const float* __restrict__ b2v, const float* __restrict__ b3v,
    const float* __restrict__ g1v, const float* __restrict__ be1v,
    const float* __restrict__ g2v, const float* __restrict__ be2v,
    const float* __restrict__ pb1,
    short* __restrict__ mhb, short* __restrict__ mwt, short* __restrict__ qwt,
    int N, int nbm)
{
  __shared__ char Hs[4][4096];   // wave-private 16x128 bf16 slices (swizzled)

  const int tid  = threadIdx.x;
  const int wv   = tid >> 6;
  const int lane = tid & 63;
  const int g    = lane >> 4;
  const int l16  = lane & 15;
  const bool is_mem = (blockIdx.x < nbm);
  const int r0   = (is_mem ? blockIdx.x : blockIdx.x - nbm) * 64 + wv * 16;
  const float* src = is_mem ? mem : query;

  int grow = r0 + l16; if (grow >= N) grow = N - 1;
  const float* xrow = src + (size_t)grow * 128 + g * 8;
  svec8 xf[4];
  #pragma unroll
  for (int ks = 0; ks < 4; ++ks) {
    f32x4 a = *(const f32x4*)(xrow + ks * 32);
    f32x4 b = *(const f32x4*)(xrow + ks * 32 + 4);
    uvec4 u;
    u[0] = pk2(a[0], a[1]); u[1] = pk2(a[2], a[3]);
    u[2] = pk2(b[0], b[1]); u[3] = pk2(b[2], b[3]);
    xf[ks] = __builtin_bit_cast(svec8, u);
  }

  if (!is_mem) {
    f32x4 acc[8];
    #pragma unroll
    for (int nf = 0; nf < 8; ++nf) { f32x4 z = {0.f,0.f,0.f,0.f}; acc[nf] = z; }
    #pragma unroll
    for (int ks = 0; ks < 4; ++ks)
      #pragma unroll
      for (int nf = 0; nf < 8; ++nf) {
        svec8 bw = *(const svec8*)(wqp + (((ks * 8 + nf) * 64 + lane) << 3));
        acc[nf] = mfma16(xf[ks], bw, acc[nf]);
      }
    #pragma unroll
    for (int nf = 0; nf < 8; ++nf) {
      float bi = pb1[nf * 16 + l16];
      #pragma unroll
      for (int r = 0; r < 4; ++r) {
        int gr = r0 + g * 4 + r;
        if (gr < N) qwt[(size_t)gr * 128 + nf * 16 + l16] = f2bf(acc[nf][r] + bi);
      }
    }
    return;
  }

  f32x4 acc[8], accm[8];
  #pragma unroll
  for (int nf = 0; nf < 8; ++nf) { f32x4 z = {0.f,0.f,0.f,0.f}; acc[nf] = z; accm[nf] = z; }
  #pragma unroll
  for (int ks = 0; ks < 4; ++ks)
    #pragma unroll
    for (int nf = 0; nf < 8; ++nf) {
      svec8 bw = *(const svec8*)(w1p + (((ks * 8 + nf) * 64 + lane) << 3));
      svec8 bm = *(const svec8*)(wmp + (((ks * 8 + nf) * 64 + lane) << 3));
      acc[nf]  = mfma16(xf[ks], bw, acc[nf]);
      accm[nf] = mfma16(xf[ks], bm, accm[nf]);
    }
  #pragma unroll
  for (int nf = 0; nf < 8; ++nf)
    #pragma unroll
    for (int r = 0; r < 4; ++r) {
      int gr = r0 + g * 4 + r;
      if (gr < N) mwt[(size_t)gr * 128 + nf * 16 + l16] = f2bf(accm[nf][r]);
    }

  char* slice = Hs[wv];

  float ps[4] = {0,0,0,0}, pq[4] = {0,0,0,0};
  #pragma unroll
  for (int nf = 0; nf < 8; ++nf) {
    float bi = b1v[nf * 16 + l16];
    #pragma unroll
    for (int r = 0; r < 4; ++r) {
      float y = fmaxf(acc[nf][r] + bi, 0.f);
      acc[nf][r] = y;
      ps[r] += y;
      pq[r] = fmaf(y, y, pq[r]);
    }
  }
  #pragma unroll
  for (int mk = 1; mk <= 8; mk <<= 1)
    #pragma unroll
    for (int r = 0; r < 4; ++r) {
      ps[r] += __shfl_xor(ps[r], mk, 64);
      pq[r] += __shfl_xor(pq[r], mk, 64);
    }
  #pragma unroll
  for (int r = 0; r < 4; ++r) {
    float mu = ps[r] * (1.f / 128.f);
    float var = fmaxf(pq[r] * (1.f / 128.f) - mu * mu, 0.f);
    float rstd = rsqrtf(var + LN_EPS);
    int rloc = g * 4 + r;
    #pragma unroll
    for (int nf = 0; nf < 8; ++nf) {
      float ga = g1v[nf * 16 + l16], bb = be1v[nf * 16 + l16];
      float z = (acc[nf][r] - mu) * rstd * ga + bb;
      int byt = (rloc * 256 + (nf * 16 + l16) * 2) ^ ((rloc & 7) << 4);
      *(short*)(slice + byt) = f2bf(z);
    }
  }

  svec8 hf[4];
  #pragma unroll
  for (int ks = 0; ks < 4; ++ks) {
    int byt = (l16 * 256 + (ks * 32 + g * 8) * 2) ^ ((l16 & 7) << 4);
    hf[ks] = *(const svec8*)(slice + byt);
  }
  f32x4 acc2[8];
  #pragma unroll
  for (int nf = 0; nf < 8; ++nf) { f32x4 z = {0.f,0.f,0.f,0.f}; acc2[nf] = z; }
  #pragma unroll
  for (int ks = 0; ks < 4; ++ks)
    #pragma unroll
    for (int nf = 0; nf < 8; ++nf) {
      svec8 bw = *(const svec8*)(w2p + (((ks * 8 + nf) * 64 + lane) << 3));
      acc2[nf] = mfma16(hf[ks], bw, acc2[nf]);
    }

  #pragma unroll
  for (int r = 0; r < 4; ++r) { ps[r] = 0.f; pq[r] = 0.f; }
  #pragma unroll
  for (int nf = 0; nf < 8; ++nf) {
    float bi = b2v[nf * 16 + l16];
    #pragma unroll
    for (int r = 0; r < 4; ++r) {
      float y = fmaxf(acc2[nf][r] + bi, 0.f);
      acc2[nf][r] = y;
      ps[r] += y;
      pq[r] = fmaf(y, y, pq[r]);
    }
  }
  #pragma unroll
  for (int mk = 1; mk <= 8; mk <<= 1)
    #pragma unroll
    for (int r = 0; r < 4; ++r) {
      ps[r] += __shfl_xor(ps[r], mk, 64);
      pq[r] += __shfl_xor(pq[r], mk, 64);
    }
  #pragma unroll
  for (int r = 0; r < 4; ++r) {
    float mu = ps[r] * (1.f / 128.f);
    float var = fmaxf(pq[r] * (1.f / 128.f) - mu * mu, 0.f);
    float rstd = rsqrtf(var + LN_EPS);
    int rloc = g * 4 + r;
    #pragma unroll
    for (int nf = 0; nf < 8; ++nf) {
      float ga = g2v[nf * 16 + l16], bb = be2v[nf * 16 + l16];
      float z = (acc2[nf][r] - mu) * rstd * ga + bb;
      int byt = (rloc * 256 + (nf * 16 + l16) * 2) ^ ((rloc & 7) << 4);
      *(short*)(slice + byt) = f2bf(z);
    }
  }

  #pragma unroll
  for (int ks = 0; ks < 4; ++ks) {
    int byt = (l16 * 256 + (ks * 32 + g * 8) * 2) ^ ((l16 & 7) << 4);
    hf[ks] = *(const svec8*)(slice + byt);
  }
  f32x4 acc3[8];
  #pragma unroll
  for (int nf = 0; nf < 8; ++nf) { f32x4 z = {0.f,0.f,0.f,0.f}; acc3[nf] = z; }
  #pragma unroll
  for (int ks = 0; ks < 4; ++ks)
    #pragma unroll
    for (int nf = 0; nf < 8; ++nf) {
      svec8 bw = *(const svec8*)(w3p + (((ks * 8 + nf) * 64 + lane) << 3));
      acc3[nf] = mfma16(hf[ks], bw, acc3[nf]);
    }
  #pragma unroll
  for (int nf = 0; nf < 8; ++nf) {
    float bi = b3v[nf * 16 + l16];
    #pragma unroll
    for (int r = 0; r < 4; ++r) {
      int gr = r0 + g * 4 + r;
      if (gr < N) mhb[(size_t)gr * 128 + nf * 16 + l16] = f2bf(acc3[nf][r] + bi);
    }
  }
}

// ---- relu(q+m) with packed f32; emits B-frags + sum/sumsq ----
__device__ __forceinline__ void relu_stats(const svec8* qv, const svec8* mv,
                                           svec8* yf, float& ps_o, float& pq_o) {
  f32x2 psv = {0.f, 0.f}, pqv = {0.f, 0.f};
  #pragma unroll
  for (int ks2 = 0; ks2 < 4; ++ks2) {
    uvec4 qu = __builtin_bit_cast(uvec4, qv[ks2]);
    uvec4 mu = __builtin_bit_cast(uvec4, mv[ks2]);
    uvec4 u;
    #pragma unroll
    for (int p = 0; p < 4; ++p) {
      f32x2 y = __builtin_elementwise_max(up2(qu[p]) + up2(mu[p]), (f32x2){0.f, 0.f});
      psv += y;
      pqv += y * y;
      u[p] = pk2(y[0], y[1]);
    }
    yf[ks2] = __builtin_bit_cast(svec8, u);
  }
  float ps = psv[0] + psv[1], pq = pqv[0] + pqv[1];
  ps += __shfl_xor(ps, 16, 64); pq += __shfl_xor(pq, 16, 64);
  ps += __shfl_xor(ps, 32, 64); pq += __shfl_xor(pq, 32, 64);
  ps_o = ps; pq_o = pq;
}

// ---------------- edge MLP: EG=2, W2' in LDS, nf-split ----------
__global__ __launch_bounds__(256, 4) void edge_mlp_kernel(
    const short* __restrict__ qwt, const short* __restrict__ mwt,
    const int* __restrict__ rowi, const int* __restrict__ coli,
    const short* __restrict__ w2p,
    const float* __restrict__ s2v, const float* __restrict__ b2pv,
    const float* __restrict__ gwv, const float* __restrict__ consts,
    float* __restrict__ hout, int E)
{
  __shared__ short w2s[16384];   // 32 KB: all W2' fragments

  const int tid  = threadIdx.x;
  const int wv   = tid >> 6;
  const int lane = tid & 63;
  const int g    = lane >> 4;
  const int l16  = lane & 15;

  // bijective XCD-aware block swizzle (m204)
  const int nb  = gridDim.x;
  const int q8  = nb >> 3, r8 = nb & 7;
  const int xcd = blockIdx.x & 7, sub = blockIdx.x >> 3;
  const int bid = (xcd < r8 ? xcd * (q8 + 1) : r8 * (q8 + 1) + (xcd - r8) * q8) + sub;

  // stage W2' fragments (linear copy)
  #pragma unroll
  for (int it = 0; it < 8; ++it) {
    int o = (it * 256 + tid) * 8;    // shorts
    *(f32x4*)(w2s + o) = *(const f32x4*)(w2p + o);
  }
  __syncthreads();

  const int eb = bid * 128 + wv * 32;
  const int e0 = eb + l16, e1 = eb + 16 + l16;
  const bool v0 = (e0 < E), v1 = (e1 < E);
  const int ee0 = v0 ? e0 : 0, ee1 = v1 ? e1 : 0;
  const short* q0 = qwt + (size_t)rowi[ee0] * 128 + g * 8;
  const short* m0 = mwt + (size_t)coli[ee0] * 128 + g * 8;
  const short* q1 = qwt + (size_t)rowi[ee1] * 128 + g * 8;
  const short* m1 = mwt + (size_t)coli[ee1] * 128 + g * 8;

  // issue all 16 gathers up front
  svec8 qv0[4], mv0[4], qv1[4], mv1[4];
  #pragma unroll
  for (int ks2 = 0; ks2 < 4; ++ks2) {
    qv0[ks2] = *(const svec8*)(q0 + ks2 * 32);
    mv0[ks2] = *(const svec8*)(m0 + ks2 * 32);
    qv1[ks2] = *(const svec8*)(q1 + ks2 * 32);
    mv1[ks2] = *(const svec8*)(m1 + ks2 * 32);
  }

  svec8 yf0[4], yf1[4];
  float ps0, pq0, ps1, pq1;
  relu_stats(qv0, mv0, yf0, ps0, pq0);
  relu_stats(qv1, mv1, yf1, ps1, pq1);
  float mu1_0   = ps0 * (1.f / 128.f);
  float rstd1_0 = rsqrtf(fmaxf(pq0 * (1.f / 128.f) - mu1_0 * mu1_0, 0.f) + LN_EPS);
  float mu1_1   = ps1 * (1.f / 128.f);
  float rstd1_1 = rsqrtf(fmaxf(pq1 * (1.f / 128.f) - mu1_1 * mu1_1, 0.f) + LN_EPS);
  float nmu0 = -rstd1_0 * mu1_0;
  float nmu1 = -rstd1_1 * mu1_1;

  // running epilogue stats carried across the two nf-halves
  f32x2 Aps = {0.f,0.f}, Apq = {0.f,0.f}, Apw = {0.f,0.f};
  f32x2 Bps = {0.f,0.f}, Bpq = {0.f,0.f}, Bpw = {0.f,0.f};

  #pragma unroll
  for (int half = 0; half < 2; ++half) {
    const int nfb = half * 4;
    f32x4 acc2a[4], acc2b[4];
    #pragma unroll
    for (int nf = 0; nf < 4; ++nf) { f32x4 z = {0.f,0.f,0.f,0.f}; acc2a[nf] = z; acc2b[nf] = z; }
    __builtin_amdgcn_s_setprio(1);
    #pragma unroll
    for (int ks2 = 0; ks2 < 4; ++ks2) {
      #pragma unroll
      for (int nf = 0; nf < 4; ++nf) {
        svec8 w = *(const svec8*)(w2s + (((ks2 * 8 + nfb + nf) * 64 + lane) << 3));
        acc2a[nf] = mfma16(w, yf0[ks2], acc2a[nf]);
        acc2b[nf] = mfma16(w, yf1[ks2], acc2b[nf]);
      }
    }
    __builtin_amdgcn_s_setprio(0);
    // partial folded epilogue for this nf-half
    #pragma unroll
    for (int nf = 0; nf < 4; ++nf) {
      f32x4 s2 = *(const f32x4*)(s2v  + (nfb + nf) * 16 + g * 4);
      f32x4 bb = *(const f32x4*)(b2pv + (nfb + nf) * 16 + g * 4);
      f32x4 gw = *(const f32x4*)(gwv  + (nfb + nf) * 16 + g * 4);
      #pragma unroll
      for (int p = 0; p < 2; ++p) {
        f32x2 s2p = { s2[2*p], s2[2*p+1] };
        f32x2 bbp = { bb[2*p], bb[2*p+1] };
        f32x2 gwp = { gw[2*p], gw[2*p+1] };
        f32x2 aa  = { acc2a[nf][2*p], acc2a[nf][2*p+1] };
        f32x2 ab  = { acc2b[nf][2*p], acc2b[nf][2*p+1] };
        f32x2 ha = (f32x2){rstd1_0, rstd1_0} * aa + ((f32x2){nmu0, nmu0} * s2p + bbp);
        f32x2 hb = (f32x2){rstd1_1, rstd1_1} * ab + ((f32x2){nmu1, nmu1} * s2p + bbp);
        f32x2 ya = __builtin_elementwise_max(ha, (f32x2){0.f, 0.f});
        f32x2 yb = __builtin_elementwise_max(hb, (f32x2){0.f, 0.f});
        Aps += ya; Apq += ya * ya; Apw += ya * gwp;
        Bps += yb; Bpq += yb * yb; Bpw += yb * gwp;
      }
    }
  }

  float Sgw = consts[0], cb = consts[1];
  float ps2a = Aps[0] + Aps[1], pq2a = Apq[0] + Apq[1], pw2a = Apw[0] + Apw[1];
  float ps2b = Bps[0] + Bps[1], pq2b = Bpq[0] + Bpq[1], pw2b = Bpw[0] + Bpw[1];
  ps2a += __shfl_xor(ps2a, 16, 64); pq2a += __shfl_xor(pq2a, 16, 64); pw2a += __shfl_xor(pw2a, 16, 64);
  ps2a += __shfl_xor(ps2a, 32, 64); pq2a += __shfl_xor(pq2a, 32, 64); pw2a += __shfl_xor(pw2a, 32, 64);
  ps2b += __shfl_xor(ps2b, 16, 64); pq2b += __shfl_xor(pq2b, 16, 64); pw2b += __shfl_xor(pw2b, 16, 64);
  ps2b += __shfl_xor(ps2b, 32, 64); pq2b += __shfl_xor(pq2b, 32, 64); pw2b += __shfl_xor(pw2b, 32, 64);
  {
    float mu2 = ps2a * (1.f / 128.f);
    float var2 = fmaxf(pq2a * (1.f / 128.f) - mu2 * mu2, 0.f);
    float rstd2 = rsqrtf(var2 + LN_EPS);
    float p3 = fmaf(rstd2, pw2a - mu2 * Sgw, cb);
    if (lane < 16 && v0) hout[e0] = tanhf(p3);
  }
  {
    float mu2 = ps2b * (1.f / 128.f);
    float var2 = fmaxf(pq2b * (1.f / 128.f) - mu2 * mu2, 0.f);
    float rstd2 = rsqrtf(var2 + LN_EPS);
    float p3 = fmaf(rstd2, pw2b - mu2 * Sgw, cb);
    if (lane < 16 && v1) hout[e1] = tanhf(p3);
  }
}

// ---------------- segment sum: full wave per node, 16 edges in flight ----------------
__global__ __launch_bounds__(256) void segsum_kernel(
    const int* __restrict__ off, const int* __restrict__ coli,
    const float* __restrict__ hbuf, const short* __restrict__ mhb,
    float* __restrict__ out, int N)
{
  int wv = threadIdx.x >> 6, lane = threadIdx.x & 63;
  int i = blockIdx.x * 4 + wv;
  if (i >= N) return;
  int s = __builtin_amdgcn_readfirstlane(off[i]);
  int e = __builtin_amdgcn_readfirstlane(off[i + 1]);
  f32x2 acc = {0.f, 0.f};
  int k = s;
  for (; k + 16 <= e; k += 16) {
    float h[16]; unsigned w[16];
    #pragma unroll
    for (int u = 0; u < 16; ++u) {
      h[u] = hbuf[k + u];
      w[u] = *(const unsigned*)(mhb + (size_t)coli[k + u] * 128 + lane * 2);
    }
    #pragma unroll
    for (int u = 0; u < 16; ++u)
      acc += (f32x2){h[u], h[u]} * up2(w[u]);
  }
  for (; k + 4 <= e; k += 4) {
    float h[4]; unsigned w[4];
    #pragma unroll
    for (int u = 0; u < 4; ++u) {
      h[u] = hbuf[k + u];
      w[u] = *(const unsigned*)(mhb + (size_t)coli[k + u] * 128 + lane * 2);
    }
    #pragma unroll
    for (int u = 0; u < 4; ++u)
      acc += (f32x2){h[u], h[u]} * up2(w[u]);
  }
  for (; k < e; ++k) {
    float h = hbuf[k];
    unsigned w = *(const unsigned*)(mhb + (size_t)coli[k] * 128 + lane * 2);
    acc += (f32x2){h, h} * up2(w);
  }
  *(f32x2*)(out + (size_t)i * 128 + lane * 2) = acc;
}

extern "C" void kernel_launch(void* const* d_in, const int* in_sizes, int n_in,
                              void* d_out, int out_size, void* d_ws, size_t ws_size,
                              hipStream_t stream) {
  const float* query = (const float*)d_in[0];
  const float* mem   = (const float*)d_in[1];
  const int*   row   = (const int*)d_in[2];
  const int*   col   = (const int*)d_in[3];
  const float* pW1 = (const float*)d_in[4];  const float* pb1 = (const float*)d_in[5];
  const float* pW2 = (const float*)d_in[6];  const float* pb2 = (const float*)d_in[7];
  const float* pW3 = (const float*)d_in[8];  const float* pb3 = (const float*)d_in[9];
  const float* pg1 = (const float*)d_in[10]; const float* pbe1 = (const float*)d_in[11];
  const float* pg2 = (const float*)d_in[12]; const float* pbe2 = (const float*)d_in[13];
  const float* mW1 = (const float*)d_in[14]; const float* mb1 = (const float*)d_in[15];
  const float* mW2 = (const float*)d_in[16]; const float* mb2 = (const float*)d_in[17];
  const float* mW3 = (const float*)d_in[18]; const float* mb3 = (const float*)d_in[19];
  const float* mg1 = (const float*)d_in[20]; const float* mbe1 = (const float*)d_in[21];
  const float* mg2 = (const float*)d_in[22]; const float* mbe2 = (const float*)d_in[23];

  const int N = in_sizes[0] / 128;
  const int E = in_sizes[2];

  char* ws = (char*)d_ws;
  short* w1qp = (short*)(ws + 0);        // 32768 B
  short* w1mp = (short*)(ws + 32768);    // 32768 B
  short* w2p  = (short*)(ws + 65536);    // 32768 B (scaled by g1)
  short* mw1p = (short*)(ws + 98304);    // 32768 B
  short* mw2p = (short*)(ws + 131072);   // 32768 B
  short* mw3p = (short*)(ws + 163840);   // 32768 B
  float* s2v  = (float*)(ws + 196608);   // 512 B
  float* b2pv = (float*)(ws + 197120);   // 512 B
  float* gwv  = (float*)(ws + 197632);   // 512 B
  float* cons = (float*)(ws + 198144);   // 64 B
  int*   offs = (int*)(ws + 198208);     // (N+1)*4
  size_t o = 198208 + (((size_t)(N + 1) * 4 + 255) / 256) * 256;
  short* qwt  = (short*)(ws + o);  o += (size_t)N * 128 * 2;   // bf16 q@W1t + b1
  short* mwt  = (short*)(ws + o);  o += (size_t)N * 128 * 2;   // bf16 m@W1b
  short* mhb  = (short*)(ws + o);  o += (size_t)N * 128 * 2;   // bf16 mem_head
  float* hbuf = (float*)(ws + o);  o += (size_t)E * 4;

  if (ws_size < o) return;

  const int nboff = (N + 1 + 255) / 256;
  setup_kernel<<<384 + nboff + 1, 256, 0, stream>>>(
      pW1, pW2, pg1, mW1, mW2, mW3, w1qp, w1mp, w2p, mw1p, mw2p, mw3p,
      row, E, N, offs,
      pg1, pbe1, pb2, pg2, pW3, pbe2, pb3, s2v, b2pv, gwv, cons, nboff);

  const int nbm = (N + 63) / 64;
  node_kernel<<<2 * nbm, 256, 0, stream>>>(
      mem, query, mw1p, mw2p, mw3p, w1mp, w1qp,
      mb1, mb2, mb3, mg1, mbe1, mg2, mbe2, pb1,
      mhb, mwt, qwt, N, nbm);

  edge_mlp_kernel<<<(E + 127) / 128, 256, 0, stream>>>(
      qwt, mwt, row, col, w2p, s2v, b2pv, gwv, cons, hbuf, E);

  segsum_kernel<<<(N + 3) / 4, 256, 0, stream>>>(offs, col, hbuf, mhb, (float*)d_out, N);
}